// Round 2
// baseline (1053.986 us; speedup 1.0000x reference)
//
#include <hip/hip_runtime.h>
#include <hip/hip_bf16.h>

#define NPAPER 100000
#define NAUTH  50000
#define NROWS  150000
#define EC 200000
#define EW 100000
#define EB 100000
#define DIM 256
#define NH 8
#define SLOPE 0.2f
#define LN_EPS 1e-5f

__device__ __forceinline__ float lrelu(float x){ return x >= 0.f ? x : SLOPE * x; }

// float atomic max via signed/unsigned int atomics (correct with -inf init)
__device__ __forceinline__ void atomicMaxF(float* a, float v){
  if (v >= 0.f) atomicMax((int*)a, __float_as_int(v));
  else          atomicMin((unsigned int*)a, (unsigned int)__float_as_int(v));
}

__global__ void fill_f32(float* __restrict__ p, float v, int n){
  int i = blockIdx.x * blockDim.x + threadIdx.x;
  int stride = gridDim.x * blockDim.x;
  for (; i < n; i += stride) p[i] = v;
}

// ---- projection: hproj[r,:] = h[r,:] @ W^T ; fused el/er head reductions ----
__global__ __launch_bounds__(256) void proj_kernel(
    const float* __restrict__ hP, const float* __restrict__ hA,
    const float* __restrict__ W, const float* __restrict__ attn_l,
    const float* __restrict__ attn_r,
    float* __restrict__ hproj, float* __restrict__ el_p, float* __restrict__ er_p,
    float* __restrict__ el_a, float* __restrict__ er_a)
{
  const int tid = threadIdx.x;
  const int r0 = blockIdx.x * 16;                 // 16 rows per block
  const bool paper = (r0 < NPAPER);
  const float* X = paper ? (hP + (size_t)r0 * DIM)
                         : (hA + (size_t)(r0 - NPAPER) * DIM);

  __shared__ float xs[16][DIM];
  for (int i = tid; i < 16 * DIM; i += 256) xs[i >> 8][i & 255] = X[i];
  __syncthreads();

  const int o = tid;                              // output column 0..255
  const float al = attn_l[o];
  const float ar = attn_r[o];

  float acc[16];
  #pragma unroll
  for (int r = 0; r < 16; r++) acc[r] = 0.f;

  const float4* wrow4 = reinterpret_cast<const float4*>(W + (size_t)o * DIM);
  for (int kk = 0; kk < DIM / 4; kk += 2){
    float4 w0 = wrow4[kk];
    float4 w1 = wrow4[kk + 1];
    #pragma unroll
    for (int r = 0; r < 16; r++){
      int k0 = kk * 4;
      float s = xs[r][k0+0]*w0.x + xs[r][k0+1]*w0.y + xs[r][k0+2]*w0.z + xs[r][k0+3]*w0.w
              + xs[r][k0+4]*w1.x + xs[r][k0+5]*w1.y + xs[r][k0+6]*w1.z + xs[r][k0+7]*w1.w;
      acc[r] += s;
    }
  }

  float* outb = hproj + (size_t)r0 * DIM;
  float* elb = paper ? (el_p + (size_t)r0 * NH) : (el_a + (size_t)(r0 - NPAPER) * NH);
  float* erb = paper ? (er_p + (size_t)r0 * NH) : (er_a + (size_t)(r0 - NPAPER) * NH);

  #pragma unroll
  for (int r = 0; r < 16; r++){
    outb[(size_t)r * DIM + o] = acc[r];
    float vl = acc[r] * al, vr = acc[r] * ar;
    #pragma unroll
    for (int m = 16; m > 0; m >>= 1){
      vl += __shfl_xor(vl, m, 32);
      vr += __shfl_xor(vr, m, 32);
    }
    if ((tid & 31) == 0){
      elb[r * NH + (o >> 5)] = vl;
      erb[r * NH + (o >> 5)] = vr;
    }
  }
}

// ---- relation/edge-type term: ee[rel,h] ----
__global__ void ee_kernel(const float* __restrict__ eEmb, const float* __restrict__ fceW,
                          const float* __restrict__ attn_e, float* __restrict__ ee)
{
  const int o = threadIdx.x;                      // 256
  const float ae = attn_e[o];
  const float* wrow = fceW + (size_t)o * DIM;
  for (int rel = 0; rel < 3; rel++){
    float acc = 0.f;
    for (int k = 0; k < DIM; k++) acc += eEmb[rel * DIM + k] * wrow[k];
    float v = acc * ae;
    #pragma unroll
    for (int m = 16; m > 0; m >>= 1) v += __shfl_xor(v, m, 32);
    if ((o & 31) == 0) ee[rel * NH + (o >> 5)] = v;
  }
}

// ---- pass 1: per-edge score + segment max ----
__global__ void edge_max_kernel(const int* __restrict__ src, const int* __restrict__ dst,
    const float* __restrict__ el, const float* __restrict__ er,
    const float* __restrict__ ee, float* __restrict__ m,
    float* __restrict__ sbuf, int E)
{
  int i = blockIdx.x * blockDim.x + threadIdx.x;
  if (i >= E * NH) return;
  int e = i >> 3, h = i & 7;
  float s = lrelu(el[(size_t)src[e] * NH + h] + er[(size_t)dst[e] * NH + h] + ee[h]);
  sbuf[i] = s;
  atomicMaxF(&m[(size_t)dst[e] * NH + h], s);
}

// ---- pass 2: exp + segment sum ----
__global__ void edge_expsum_kernel(const int* __restrict__ dst,
    const float* __restrict__ m, float* __restrict__ z,
    float* __restrict__ sbuf, int E)
{
  int i = blockIdx.x * blockDim.x + threadIdx.x;
  if (i >= E * NH) return;
  int e = i >> 3, h = i & 7;
  int d = dst[e];
  float w = expf(sbuf[i] - m[(size_t)d * NH + h]);
  sbuf[i] = w;
  atomicAdd(&z[(size_t)d * NH + h], w);
}

// ---- pass 3: weighted scatter aggregation; one block per edge ----
__global__ __launch_bounds__(256) void agg_kernel(
    const int* __restrict__ src, const int* __restrict__ dst,
    const float* __restrict__ srcfeat, const float* __restrict__ w,
    const float* __restrict__ z, float* __restrict__ t, int E)
{
  int e = blockIdx.x;
  int c = threadIdx.x;
  int s = src[e], d = dst[e];
  float a = w[(size_t)e * NH + (c >> 5)] / z[(size_t)d * NH + (c >> 5)];
  atomicAdd(&t[(size_t)d * DIM + c], srcfeat[(size_t)s * DIM + c] * a);
}

// ---- epilogue: residual + leaky + layernorm, f32 out ----
__global__ __launch_bounds__(64) void ln_kernel(const float* __restrict__ t,
  const float* __restrict__ hproj, const float* __restrict__ gamma,
  const float* __restrict__ beta, float* __restrict__ out)
{
  const int r = blockIdx.x;
  const int lane = threadIdx.x;
  const float* tr = t + (size_t)r * DIM;
  const float* hr = hproj + (size_t)r * DIM;
  float x[4]; float s = 0.f, q = 0.f;
  #pragma unroll
  for (int j = 0; j < 4; j++){
    int c = lane + 64 * j;
    x[j] = lrelu(tr[c] + hr[c]);
    s += x[j]; q += x[j] * x[j];
  }
  #pragma unroll
  for (int msk = 32; msk > 0; msk >>= 1){
    s += __shfl_xor(s, msk, 64);
    q += __shfl_xor(q, msk, 64);
  }
  float mu  = s * (1.f / DIM);
  float var = q * (1.f / DIM) - mu * mu;
  float inv = rsqrtf(var + LN_EPS);
  #pragma unroll
  for (int j = 0; j < 4; j++){
    int c = lane + 64 * j;
    float y = (x[j] - mu) * inv * gamma[c] + beta[c];
    out[(size_t)r * DIM + c] = y;
  }
}

extern "C" void kernel_launch(void* const* d_in, const int* in_sizes, int n_in,
                              void* d_out, int out_size, void* d_ws, size_t ws_size,
                              hipStream_t stream)
{
  const float* hP     = (const float*)d_in[0];
  const float* hA     = (const float*)d_in[1];
  const float* fcW    = (const float*)d_in[2];
  const float* fceW   = (const float*)d_in[3];
  const float* eEmb   = (const float*)d_in[4];
  const float* attn_l = (const float*)d_in[5];
  const float* attn_r = (const float*)d_in[6];
  const float* attn_e = (const float*)d_in[7];
  const float* gamma  = (const float*)d_in[8];
  const float* beta   = (const float*)d_in[9];
  const int* c_src  = (const int*)d_in[10];
  const int* c_dst  = (const int*)d_in[11];
  const int* w_src  = (const int*)d_in[12];
  const int* w_dst  = (const int*)d_in[13];
  const int* b_src  = (const int*)d_in[14];
  const int* b_dst  = (const int*)d_in[15];

  float* hproj = (float*)d_ws;                          // [NROWS,256] papers then authors
  float* tacc  = hproj + (size_t)NROWS * DIM;           // [NROWS,256]
  float* zacc  = tacc  + (size_t)NROWS * DIM;           // [NROWS,8]
  float* macc  = zacc  + (size_t)NROWS * NH;            // [NROWS,8]
  float* el_p  = macc  + (size_t)NROWS * NH;
  float* er_p  = el_p  + (size_t)NPAPER * NH;
  float* el_a  = er_p  + (size_t)NPAPER * NH;
  float* er_a  = el_a  + (size_t)NAUTH * NH;
  float* eew   = er_a  + (size_t)NAUTH * NH;            // 24 (+pad)
  float* s_c   = eew + 32;                              // per-edge scores/weights
  float* s_w   = s_c + (size_t)EC * NH;
  float* s_b   = s_w + (size_t)EW * NH;

  // zero t and z (adjacent), m = -inf
  int nzero = NROWS * DIM + NROWS * NH;
  fill_f32<<<2048, 256, 0, stream>>>(tacc, 0.f, nzero);
  fill_f32<<<512, 256, 0, stream>>>(macc, -INFINITY, NROWS * NH);

  proj_kernel<<<NROWS / 16, 256, 0, stream>>>(hP, hA, fcW, attn_l, attn_r,
                                              hproj, el_p, er_p, el_a, er_a);
  ee_kernel<<<1, 256, 0, stream>>>(eEmb, fceW, attn_e, eew);

  float* z_p = zacc; float* z_a = zacc + (size_t)NPAPER * NH;
  float* m_p = macc; float* m_a = macc + (size_t)NPAPER * NH;
  float* t_p = tacc; float* t_a = tacc + (size_t)NPAPER * DIM;
  float* ha_ = hproj + (size_t)NPAPER * DIM;

  const int TB = 256;
  edge_max_kernel<<<(EC * NH + TB - 1) / TB, TB, 0, stream>>>(c_src, c_dst, el_p, er_p, eew + 0,  m_p, s_c, EC);
  edge_max_kernel<<<(EW * NH + TB - 1) / TB, TB, 0, stream>>>(w_src, w_dst, el_a, er_p, eew + 8,  m_p, s_w, EW);
  edge_max_kernel<<<(EB * NH + TB - 1) / TB, TB, 0, stream>>>(b_src, b_dst, el_p, er_a, eew + 16, m_a, s_b, EB);

  edge_expsum_kernel<<<(EC * NH + TB - 1) / TB, TB, 0, stream>>>(c_dst, m_p, z_p, s_c, EC);
  edge_expsum_kernel<<<(EW * NH + TB - 1) / TB, TB, 0, stream>>>(w_dst, m_p, z_p, s_w, EW);
  edge_expsum_kernel<<<(EB * NH + TB - 1) / TB, TB, 0, stream>>>(b_dst, m_a, z_a, s_b, EB);

  agg_kernel<<<EC, 256, 0, stream>>>(c_src, c_dst, hproj, s_c, z_p, t_p, EC);
  agg_kernel<<<EW, 256, 0, stream>>>(w_src, w_dst, ha_,   s_w, z_p, t_p, EW);
  agg_kernel<<<EB, 256, 0, stream>>>(b_src, b_dst, hproj, s_b, z_a, t_a, EB);

  ln_kernel<<<NROWS, 64, 0, stream>>>(tacc, hproj, gamma, beta, (float*)d_out);
}

// Round 3
// 675.757 us; speedup vs baseline: 1.5597x; 1.5597x over previous
//
#include <hip/hip_runtime.h>
#include <hip/hip_bf16.h>

#define NPAPER 100000
#define NAUTH  50000
#define NROWS  150000
#define EC 200000
#define EW 100000
#define EB 100000
#define DIM 256
#define NH 8
#define SLOPE 0.2f
#define LN_EPS 1e-5f

typedef unsigned short u16;
typedef __attribute__((ext_vector_type(8))) short s16x8;
typedef __attribute__((ext_vector_type(4))) float f32x4;

__device__ __forceinline__ float lrelu(float x){ return x >= 0.f ? x : SLOPE * x; }
__device__ __forceinline__ u16 f2b(float f){
  __hip_bfloat16 b = __float2bfloat16(f);
  return *reinterpret_cast<u16*>(&b);
}

__global__ void fill_f32(float* __restrict__ p, float v, int n){
  int i = blockIdx.x * blockDim.x + threadIdx.x;
  int stride = gridDim.x * blockDim.x;
  for (; i < n; i += stride) p[i] = v;
}

// ---- W f32 -> bf16 (once per launch; 65536 elems) ----
__global__ void convert_w(const float4* __restrict__ W4, ushort4* __restrict__ Wb4){
  int i = blockIdx.x * blockDim.x + threadIdx.x;   // 16384 threads
  float4 v = W4[i];
  ushort4 o; o.x = f2b(v.x); o.y = f2b(v.y); o.z = f2b(v.z); o.w = f2b(v.w);
  Wb4[i] = o;
}

// ---- projection via MFMA: out[r,:] = X[r,:] @ W^T (W bf16 [256][256]) ----
// block = 256 thr (4 waves), tile 64 rows x 256 cols; wave w owns cols w*64..+63
#define XPAD 264
__global__ __launch_bounds__(256) void proj_mfma(
    const float* __restrict__ X, const u16* __restrict__ Wb,
    float* __restrict__ out, int nrows)
{
  const int tid = threadIdx.x;
  const int r0 = blockIdx.x * 64;
  __shared__ u16 xs[64][XPAD];

  // stage 64x256 f32 -> bf16 LDS
  for (int i = tid; i < 64 * 64; i += 256){
    int row = i >> 6, c4 = (i & 63) << 2;
    int gr = r0 + row;
    float4 v;
    if (gr < nrows) v = *reinterpret_cast<const float4*>(X + (size_t)gr * DIM + c4);
    else { v.x = v.y = v.z = v.w = 0.f; }
    ushort4 o; o.x = f2b(v.x); o.y = f2b(v.y); o.z = f2b(v.z); o.w = f2b(v.w);
    *reinterpret_cast<ushort4*>(&xs[row][c4]) = o;
  }
  __syncthreads();

  const int l = tid & 63, wid = tid >> 6;
  const int lrow = l & 15;
  const int lk8 = (l >> 4) * 8;
  const int n0 = wid * 64;

  f32x4 acc[4][4];
  #pragma unroll
  for (int mi = 0; mi < 4; mi++)
    #pragma unroll
    for (int ni = 0; ni < 4; ni++) acc[mi][ni] = (f32x4){0.f, 0.f, 0.f, 0.f};

  #pragma unroll
  for (int kk = 0; kk < DIM; kk += 32){
    s16x8 aF[4], bF[4];
    #pragma unroll
    for (int mi = 0; mi < 4; mi++)
      aF[mi] = *reinterpret_cast<const s16x8*>(&xs[mi * 16 + lrow][kk + lk8]);
    #pragma unroll
    for (int ni = 0; ni < 4; ni++){
      int col = n0 + ni * 16 + lrow;
      bF[ni] = *reinterpret_cast<const s16x8*>(Wb + (size_t)col * DIM + kk + lk8);
    }
    #pragma unroll
    for (int mi = 0; mi < 4; mi++)
      #pragma unroll
      for (int ni = 0; ni < 4; ni++)
        acc[mi][ni] = __builtin_amdgcn_mfma_f32_16x16x32_bf16(aF[mi], bF[ni], acc[mi][ni], 0, 0, 0);
  }

  // store: C frag layout col=lane&15, row=(lane>>4)*4+reg  [m89-verified]
  #pragma unroll
  for (int mi = 0; mi < 4; mi++){
    int rbase = r0 + mi * 16 + (l >> 4) * 4;
    #pragma unroll
    for (int ni = 0; ni < 4; ni++){
      int col = n0 + ni * 16 + lrow;
      #pragma unroll
      for (int reg = 0; reg < 4; reg++){
        int r = rbase + reg;
        if (r < nrows) out[(size_t)r * DIM + col] = acc[mi][ni][reg];
      }
    }
  }
}

// ---- el/er head reductions over hproj: one wave per row ----
__global__ __launch_bounds__(256) void elr_kernel(const float* __restrict__ hproj,
    const float* __restrict__ attn_l, const float* __restrict__ attn_r,
    float* __restrict__ el_p, float* __restrict__ er_p,
    float* __restrict__ el_a, float* __restrict__ er_a)
{
  const int wid = threadIdx.x >> 6, l = threadIdx.x & 63;
  const int row = blockIdx.x * 4 + wid;
  if (row >= NROWS) return;
  float4 v  = *reinterpret_cast<const float4*>(hproj + (size_t)row * DIM + l * 4);
  float4 al = *reinterpret_cast<const float4*>(attn_l + l * 4);
  float4 ar = *reinterpret_cast<const float4*>(attn_r + l * 4);
  float sl = v.x*al.x + v.y*al.y + v.z*al.z + v.w*al.w;
  float sr = v.x*ar.x + v.y*ar.y + v.z*ar.z + v.w*ar.w;
  #pragma unroll
  for (int m = 1; m < 8; m <<= 1){
    sl += __shfl_xor(sl, m, 64);
    sr += __shfl_xor(sr, m, 64);
  }
  if ((l & 7) == 0){
    int h = l >> 3;
    if (row < NPAPER){ el_p[(size_t)row*NH+h] = sl; er_p[(size_t)row*NH+h] = sr; }
    else { el_a[(size_t)(row-NPAPER)*NH+h] = sl; er_a[(size_t)(row-NPAPER)*NH+h] = sr; }
  }
}

// ---- relation/edge-type term: ee[rel,h] ----
__global__ void ee_kernel(const float* __restrict__ eEmb, const float* __restrict__ fceW,
                          const float* __restrict__ attn_e, float* __restrict__ ee)
{
  const int o = threadIdx.x;                      // 256
  const float ae = attn_e[o];
  const float* wrow = fceW + (size_t)o * DIM;
  for (int rel = 0; rel < 3; rel++){
    float acc = 0.f;
    for (int k = 0; k < DIM; k++) acc += eEmb[rel * DIM + k] * wrow[k];
    float v = acc * ae;
    #pragma unroll
    for (int m = 16; m > 0; m >>= 1) v += __shfl_xor(v, m, 32);
    if ((o & 31) == 0) ee[rel * NH + (o >> 5)] = v;
  }
}

// ---- single softmax pass: w = exp(score) (no max shift; scores bounded), sum z ----
__global__ void edge_w_kernel(const int* __restrict__ src, const int* __restrict__ dst,
    const float* __restrict__ el, const float* __restrict__ er,
    const float* __restrict__ ee, float* __restrict__ z,
    float* __restrict__ sbuf, int E)
{
  int i = blockIdx.x * blockDim.x + threadIdx.x;
  if (i >= E * NH) return;
  int e = i >> 3, h = i & 7;
  float s = lrelu(el[(size_t)src[e] * NH + h] + er[(size_t)dst[e] * NH + h] + ee[h]);
  float w = __expf(s);
  sbuf[i] = w;
  atomicAdd(&z[(size_t)dst[e] * NH + h], w);
}

// ---- weighted scatter aggregation; one block per edge ----
__global__ __launch_bounds__(256) void agg_kernel(
    const int* __restrict__ src, const int* __restrict__ dst,
    const float* __restrict__ srcfeat, const float* __restrict__ w,
    const float* __restrict__ z, float* __restrict__ t, int E)
{
  int e = blockIdx.x;
  int c = threadIdx.x;
  int s = src[e], d = dst[e];
  float a = w[(size_t)e * NH + (c >> 5)] / z[(size_t)d * NH + (c >> 5)];
  atomicAdd(&t[(size_t)d * DIM + c], srcfeat[(size_t)s * DIM + c] * a);
}

// ---- epilogue: residual + leaky + layernorm ----
__global__ __launch_bounds__(64) void ln_kernel(const float* __restrict__ t,
  const float* __restrict__ hproj, const float* __restrict__ gamma,
  const float* __restrict__ beta, float* __restrict__ out)
{
  const int r = blockIdx.x;
  const int lane = threadIdx.x;
  const float* tr = t + (size_t)r * DIM;
  const float* hr = hproj + (size_t)r * DIM;
  float x[4]; float s = 0.f, q = 0.f;
  #pragma unroll
  for (int j = 0; j < 4; j++){
    int c = lane + 64 * j;
    x[j] = lrelu(tr[c] + hr[c]);
    s += x[j]; q += x[j] * x[j];
  }
  #pragma unroll
  for (int msk = 32; msk > 0; msk >>= 1){
    s += __shfl_xor(s, msk, 64);
    q += __shfl_xor(q, msk, 64);
  }
  float mu  = s * (1.f / DIM);
  float var = q * (1.f / DIM) - mu * mu;
  float inv = rsqrtf(var + LN_EPS);
  #pragma unroll
  for (int j = 0; j < 4; j++){
    int c = lane + 64 * j;
    out[(size_t)r * DIM + c] = (x[j] - mu) * inv * gamma[c] + beta[c];
  }
}

extern "C" void kernel_launch(void* const* d_in, const int* in_sizes, int n_in,
                              void* d_out, int out_size, void* d_ws, size_t ws_size,
                              hipStream_t stream)
{
  const float* hP     = (const float*)d_in[0];
  const float* hA     = (const float*)d_in[1];
  const float* fcW    = (const float*)d_in[2];
  const float* fceW   = (const float*)d_in[3];
  const float* eEmb   = (const float*)d_in[4];
  const float* attn_l = (const float*)d_in[5];
  const float* attn_r = (const float*)d_in[6];
  const float* attn_e = (const float*)d_in[7];
  const float* gamma  = (const float*)d_in[8];
  const float* beta   = (const float*)d_in[9];
  const int* c_src  = (const int*)d_in[10];
  const int* c_dst  = (const int*)d_in[11];
  const int* w_src  = (const int*)d_in[12];
  const int* w_dst  = (const int*)d_in[13];
  const int* b_src  = (const int*)d_in[14];
  const int* b_dst  = (const int*)d_in[15];

  float* hproj = (float*)d_ws;                          // [NROWS,256] papers then authors
  float* tacc  = hproj + (size_t)NROWS * DIM;           // [NROWS,256]
  float* zacc  = tacc  + (size_t)NROWS * DIM;           // [NROWS,8]
  float* el_p  = zacc  + (size_t)NROWS * NH;
  float* er_p  = el_p  + (size_t)NPAPER * NH;
  float* el_a  = er_p  + (size_t)NPAPER * NH;
  float* er_a  = el_a  + (size_t)NAUTH * NH;
  float* eew   = er_a  + (size_t)NAUTH * NH;            // 24 (+pad to 32)
  float* s_c   = eew + 32;                              // per-edge weights
  float* s_w   = s_c + (size_t)EC * NH;
  float* s_b   = s_w + (size_t)EW * NH;
  u16*   Wb    = (u16*)(s_b + (size_t)EB * NH);         // bf16 W [256*256]

  // zero t and z (adjacent)
  fill_f32<<<4096, 256, 0, stream>>>(tacc, 0.f, NROWS * DIM + NROWS * NH);

  convert_w<<<64, 256, 0, stream>>>((const float4*)fcW, (ushort4*)Wb);

  proj_mfma<<<(NPAPER + 63) / 64, 256, 0, stream>>>(hP, Wb, hproj, NPAPER);
  proj_mfma<<<(NAUTH  + 63) / 64, 256, 0, stream>>>(hA, Wb, hproj + (size_t)NPAPER * DIM, NAUTH);

  elr_kernel<<<(NROWS + 3) / 4, 256, 0, stream>>>(hproj, attn_l, attn_r,
                                                  el_p, er_p, el_a, er_a);
  ee_kernel<<<1, 256, 0, stream>>>(eEmb, fceW, attn_e, eew);

  float* z_p = zacc; float* z_a = zacc + (size_t)NPAPER * NH;
  float* t_p = tacc; float* t_a = tacc + (size_t)NPAPER * DIM;
  float* ha_ = hproj + (size_t)NPAPER * DIM;

  const int TB = 256;
  edge_w_kernel<<<(EC * NH + TB - 1) / TB, TB, 0, stream>>>(c_src, c_dst, el_p, er_p, eew + 0,  z_p, s_c, EC);
  edge_w_kernel<<<(EW * NH + TB - 1) / TB, TB, 0, stream>>>(w_src, w_dst, el_a, er_p, eew + 8,  z_p, s_w, EW);
  edge_w_kernel<<<(EB * NH + TB - 1) / TB, TB, 0, stream>>>(b_src, b_dst, el_p, er_a, eew + 16, z_a, s_b, EB);

  agg_kernel<<<EC, 256, 0, stream>>>(c_src, c_dst, hproj, s_c, z_p, t_p, EC);
  agg_kernel<<<EW, 256, 0, stream>>>(w_src, w_dst, ha_,   s_w, z_p, t_p, EW);
  agg_kernel<<<EB, 256, 0, stream>>>(b_src, b_dst, hproj, s_b, z_a, t_a, EB);

  ln_kernel<<<NROWS, 64, 0, stream>>>(tacc, hproj, gamma, beta, (float*)d_out);
}

// Round 4
// 345.396 us; speedup vs baseline: 3.0515x; 1.9565x over previous
//
#include <hip/hip_runtime.h>
#include <hip/hip_bf16.h>

#define NPAPER 100000
#define NAUTH  50000
#define NROWS  150000
#define EC 200000
#define EW 100000
#define EB 100000
#define DIM 256
#define NH 8
#define SLOPE 0.2f
#define LN_EPS 1e-5f

typedef unsigned short u16;
typedef __attribute__((ext_vector_type(8))) short s16x8;
typedef __attribute__((ext_vector_type(4))) float f32x4;

__device__ __forceinline__ float lrelu(float x){ return x >= 0.f ? x : SLOPE * x; }
__device__ __forceinline__ u16 f2b(float f){
  __hip_bfloat16 b = __float2bfloat16(f);
  return *reinterpret_cast<u16*>(&b);
}

__global__ void fill_i32(int* __restrict__ p, int v, int n){
  int i = blockIdx.x * blockDim.x + threadIdx.x;
  int stride = gridDim.x * blockDim.x;
  for (; i < n; i += stride) p[i] = v;
}

// ---- W f32 -> bf16 ----
__global__ void convert_w(const float4* __restrict__ W4, ushort4* __restrict__ Wb4){
  int i = blockIdx.x * blockDim.x + threadIdx.x;   // 16384 threads
  float4 v = W4[i];
  ushort4 o; o.x = f2b(v.x); o.y = f2b(v.y); o.z = f2b(v.z); o.w = f2b(v.w);
  Wb4[i] = o;
}

// ---- projection via MFMA: out[r,:] = X[r,:] @ W^T (W bf16 [256][256]) ----
#define XPAD 264
__global__ __launch_bounds__(256) void proj_mfma(
    const float* __restrict__ X, const u16* __restrict__ Wb,
    float* __restrict__ out, int nrows)
{
  const int tid = threadIdx.x;
  const int r0 = blockIdx.x * 64;
  __shared__ u16 xs[64][XPAD];

  for (int i = tid; i < 64 * 64; i += 256){
    int row = i >> 6, c4 = (i & 63) << 2;
    int gr = r0 + row;
    float4 v;
    if (gr < nrows) v = *reinterpret_cast<const float4*>(X + (size_t)gr * DIM + c4);
    else { v.x = v.y = v.z = v.w = 0.f; }
    ushort4 o; o.x = f2b(v.x); o.y = f2b(v.y); o.z = f2b(v.z); o.w = f2b(v.w);
    *reinterpret_cast<ushort4*>(&xs[row][c4]) = o;
  }
  __syncthreads();

  const int l = tid & 63, wid = tid >> 6;
  const int lrow = l & 15;
  const int lk8 = (l >> 4) * 8;
  const int n0 = wid * 64;

  f32x4 acc[4][4];
  #pragma unroll
  for (int mi = 0; mi < 4; mi++)
    #pragma unroll
    for (int ni = 0; ni < 4; ni++) acc[mi][ni] = (f32x4){0.f, 0.f, 0.f, 0.f};

  #pragma unroll
  for (int kk = 0; kk < DIM; kk += 32){
    s16x8 aF[4], bF[4];
    #pragma unroll
    for (int mi = 0; mi < 4; mi++)
      aF[mi] = *reinterpret_cast<const s16x8*>(&xs[mi * 16 + lrow][kk + lk8]);
    #pragma unroll
    for (int ni = 0; ni < 4; ni++){
      int col = n0 + ni * 16 + lrow;
      bF[ni] = *reinterpret_cast<const s16x8*>(Wb + (size_t)col * DIM + kk + lk8);
    }
    #pragma unroll
    for (int mi = 0; mi < 4; mi++)
      #pragma unroll
      for (int ni = 0; ni < 4; ni++)
        acc[mi][ni] = __builtin_amdgcn_mfma_f32_16x16x32_bf16(aF[mi], bF[ni], acc[mi][ni], 0, 0, 0);
  }

  #pragma unroll
  for (int mi = 0; mi < 4; mi++){
    int rbase = r0 + mi * 16 + (l >> 4) * 4;
    #pragma unroll
    for (int ni = 0; ni < 4; ni++){
      int col = n0 + ni * 16 + lrow;
      #pragma unroll
      for (int reg = 0; reg < 4; reg++){
        int r = rbase + reg;
        if (r < nrows) out[(size_t)r * DIM + col] = acc[mi][ni][reg];
      }
    }
  }
}

// ---- el/er head reductions over hproj (unified [NROWS][8]) ----
__global__ __launch_bounds__(256) void elr_kernel(const float* __restrict__ hproj,
    const float* __restrict__ attn_l, const float* __restrict__ attn_r,
    float* __restrict__ el, float* __restrict__ er)
{
  const int wid = threadIdx.x >> 6, l = threadIdx.x & 63;
  const int row = blockIdx.x * 4 + wid;
  if (row >= NROWS) return;
  float4 v  = *reinterpret_cast<const float4*>(hproj + (size_t)row * DIM + l * 4);
  float4 al = *reinterpret_cast<const float4*>(attn_l + l * 4);
  float4 ar = *reinterpret_cast<const float4*>(attn_r + l * 4);
  float sl = v.x*al.x + v.y*al.y + v.z*al.z + v.w*al.w;
  float sr = v.x*ar.x + v.y*ar.y + v.z*ar.z + v.w*ar.w;
  #pragma unroll
  for (int m = 1; m < 8; m <<= 1){
    sl += __shfl_xor(sl, m, 64);
    sr += __shfl_xor(sr, m, 64);
  }
  if ((l & 7) == 0){
    int h = l >> 3;
    el[(size_t)row*NH+h] = sl;
    er[(size_t)row*NH+h] = sr;
  }
}

// ---- relation/edge-type term ----
__global__ void ee_kernel(const float* __restrict__ eEmb, const float* __restrict__ fceW,
                          const float* __restrict__ attn_e, float* __restrict__ ee)
{
  const int o = threadIdx.x;
  const float ae = attn_e[o];
  const float* wrow = fceW + (size_t)o * DIM;
  for (int rel = 0; rel < 3; rel++){
    float acc = 0.f;
    for (int k = 0; k < DIM; k++) acc += eEmb[rel * DIM + k] * wrow[k];
    float v = acc * ae;
    #pragma unroll
    for (int m = 16; m > 0; m >>= 1) v += __shfl_xor(v, m, 32);
    if ((o & 31) == 0) ee[rel * NH + (o >> 5)] = v;
  }
}

// ---- CSR build ----
__global__ void count_kernel(const int* __restrict__ dst, int E, int dstOff,
                             int* __restrict__ counts){
  int i = blockIdx.x * blockDim.x + threadIdx.x;
  if (i < E) atomicAdd(&counts[dstOff + dst[i]], 1);
}

__global__ void scan1(const int* __restrict__ in, int* __restrict__ out,
                      int* __restrict__ bsum, int n){
  __shared__ int sh[256];
  int b = blockIdx.x, t = threadIdx.x;
  int base = b * 1024 + t * 4;
  int v0 = (base+0 < n) ? in[base+0] : 0;
  int v1 = (base+1 < n) ? in[base+1] : 0;
  int v2 = (base+2 < n) ? in[base+2] : 0;
  int v3 = (base+3 < n) ? in[base+3] : 0;
  sh[t] = v0+v1+v2+v3;
  __syncthreads();
  for (int off = 1; off < 256; off <<= 1){
    int x = (t >= off) ? sh[t-off] : 0;
    __syncthreads();
    sh[t] += x;
    __syncthreads();
  }
  if (t == 255) bsum[b] = sh[255];
  int run = (t > 0) ? sh[t-1] : 0;
  if (base+0 < n){ out[base+0] = run; run += v0; }
  if (base+1 < n){ out[base+1] = run; run += v1; }
  if (base+2 < n){ out[base+2] = run; run += v2; }
  if (base+3 < n){ out[base+3] = run; }
}

__global__ void scan2(int* __restrict__ bsum, int nb){
  __shared__ int sh[256];
  int t = threadIdx.x;
  sh[t] = (t < nb) ? bsum[t] : 0;
  __syncthreads();
  for (int off = 1; off < 256; off <<= 1){
    int x = (t >= off) ? sh[t-off] : 0;
    __syncthreads();
    sh[t] += x;
    __syncthreads();
  }
  int excl = (t > 0) ? sh[t-1] : 0;
  if (t < nb) bsum[t] = excl;
}

__global__ void scan3(int* __restrict__ rowptr, const int* __restrict__ bsum, int n){
  int i = blockIdx.x * blockDim.x + threadIdx.x;
  if (i < n) rowptr[i] += bsum[i >> 10];
}

__global__ void scatter_kernel(const int* __restrict__ src, const int* __restrict__ dst,
                               int E, int srcOff, int dstOff, int rel,
                               const int* __restrict__ rowptr, int* __restrict__ cursor,
                               int* __restrict__ eidx){
  int i = blockIdx.x * blockDim.x + threadIdx.x;
  if (i >= E) return;
  int gd = dstOff + dst[i];
  int pos = rowptr[gd] + atomicAdd(&cursor[gd], 1);
  eidx[pos] = (srcOff + src[i]) | (rel << 20);
}

// ---- fused: softmax-z + weighted gather + residual + LN; one wave per row ----
__global__ __launch_bounds__(256) void agg_ln_kernel(
    const int* __restrict__ rowptr, const int* __restrict__ counts,
    const int* __restrict__ eidx, const float* __restrict__ hproj,
    const float* __restrict__ el, const float* __restrict__ er,
    const float* __restrict__ eew, const float* __restrict__ gamma,
    const float* __restrict__ beta, float* __restrict__ out)
{
  const int wid = threadIdx.x >> 6, l = threadIdx.x & 63;
  const int r = blockIdx.x * 4 + wid;
  if (r >= NROWS) return;
  const int h = l >> 3;                           // cols 4l..4l+3 share head
  const float er_h = er[(size_t)r * NH + h];
  const int rp = rowptr[r], deg = counts[r];

  float ax = 0.f, ay = 0.f, az = 0.f, aw = 0.f, zl = 0.f;
  for (int e = 0; e < deg; e++){
    int p = eidx[rp + e];
    int gs = p & 0xFFFFF, rel = p >> 20;
    float sc = el[(size_t)gs * NH + h] + er_h + eew[rel * NH + h];
    float w = __expf(lrelu(sc));
    zl += w;
    const float4 f = *reinterpret_cast<const float4*>(hproj + (size_t)gs * DIM + l * 4);
    ax += w * f.x; ay += w * f.y; az += w * f.z; aw += w * f.w;
  }
  float iz = (deg > 0) ? 1.f / zl : 0.f;
  const float4 hres = *reinterpret_cast<const float4*>(hproj + (size_t)r * DIM + l * 4);
  float x0 = lrelu(ax * iz + hres.x);
  float x1 = lrelu(ay * iz + hres.y);
  float x2 = lrelu(az * iz + hres.z);
  float x3 = lrelu(aw * iz + hres.w);
  float s = x0 + x1 + x2 + x3;
  float q = x0*x0 + x1*x1 + x2*x2 + x3*x3;
  #pragma unroll
  for (int m = 32; m > 0; m >>= 1){
    s += __shfl_xor(s, m, 64);
    q += __shfl_xor(q, m, 64);
  }
  float mu  = s * (1.f / DIM);
  float var = q * (1.f / DIM) - mu * mu;
  float inv = rsqrtf(var + LN_EPS);
  float4 g  = *reinterpret_cast<const float4*>(gamma + l * 4);
  float4 bt = *reinterpret_cast<const float4*>(beta + l * 4);
  float4 o;
  o.x = (x0 - mu) * inv * g.x + bt.x;
  o.y = (x1 - mu) * inv * g.y + bt.y;
  o.z = (x2 - mu) * inv * g.z + bt.z;
  o.w = (x3 - mu) * inv * g.w + bt.w;
  *reinterpret_cast<float4*>(out + (size_t)r * DIM + l * 4) = o;
}

extern "C" void kernel_launch(void* const* d_in, const int* in_sizes, int n_in,
                              void* d_out, int out_size, void* d_ws, size_t ws_size,
                              hipStream_t stream)
{
  const float* hP     = (const float*)d_in[0];
  const float* hA     = (const float*)d_in[1];
  const float* fcW    = (const float*)d_in[2];
  const float* fceW   = (const float*)d_in[3];
  const float* eEmb   = (const float*)d_in[4];
  const float* attn_l = (const float*)d_in[5];
  const float* attn_r = (const float*)d_in[6];
  const float* attn_e = (const float*)d_in[7];
  const float* gamma  = (const float*)d_in[8];
  const float* beta   = (const float*)d_in[9];
  const int* c_src  = (const int*)d_in[10];
  const int* c_dst  = (const int*)d_in[11];
  const int* w_src  = (const int*)d_in[12];
  const int* w_dst  = (const int*)d_in[13];
  const int* b_src  = (const int*)d_in[14];
  const int* b_dst  = (const int*)d_in[15];

  float* hproj = (float*)d_ws;                          // [NROWS,256]
  float* el    = hproj + (size_t)NROWS * DIM;           // [NROWS,8]
  float* er    = el    + (size_t)NROWS * NH;            // [NROWS,8]
  float* eew   = er    + (size_t)NROWS * NH;            // 24 (+pad 32)
  int*   counts= (int*)(eew + 32);                      // [NROWS]
  int*   cursor= counts + NROWS;                        // [NROWS]
  int*   rowptr= cursor + NROWS;                        // [NROWS]
  int*   bsum  = rowptr + NROWS;                        // [256]
  int*   eidx  = bsum + 256;                            // [400000]
  u16*   Wb    = (u16*)(eidx + (EC + EW + EB));         // bf16 W

  const int TB = 256;

  // CSR build (independent of projection)
  fill_i32<<<256, TB, 0, stream>>>(counts, 0, 2 * NROWS);   // counts + cursor
  count_kernel<<<(EC + TB - 1) / TB, TB, 0, stream>>>(c_dst, EC, 0,      counts);
  count_kernel<<<(EW + TB - 1) / TB, TB, 0, stream>>>(w_dst, EW, 0,      counts);
  count_kernel<<<(EB + TB - 1) / TB, TB, 0, stream>>>(b_dst, EB, NPAPER, counts);
  const int NB = (NROWS + 1023) / 1024;                     // 147
  scan1<<<NB, TB, 0, stream>>>(counts, rowptr, bsum, NROWS);
  scan2<<<1, TB, 0, stream>>>(bsum, NB);
  scan3<<<(NROWS + TB - 1) / TB, TB, 0, stream>>>(rowptr, bsum, NROWS);
  scatter_kernel<<<(EC + TB - 1) / TB, TB, 0, stream>>>(c_src, c_dst, EC, 0,      0,      0, rowptr, cursor, eidx);
  scatter_kernel<<<(EW + TB - 1) / TB, TB, 0, stream>>>(w_src, w_dst, EW, NPAPER, 0,      1, rowptr, cursor, eidx);
  scatter_kernel<<<(EB + TB - 1) / TB, TB, 0, stream>>>(b_src, b_dst, EB, 0,      NPAPER, 2, rowptr, cursor, eidx);

  // projection + attention scalars
  convert_w<<<64, TB, 0, stream>>>((const float4*)fcW, (ushort4*)Wb);
  proj_mfma<<<(NPAPER + 63) / 64, TB, 0, stream>>>(hP, Wb, hproj, NPAPER);
  proj_mfma<<<(NAUTH  + 63) / 64, TB, 0, stream>>>(hA, Wb, hproj + (size_t)NPAPER * DIM, NAUTH);
  elr_kernel<<<(NROWS + 3) / 4, TB, 0, stream>>>(hproj, attn_l, attn_r, el, er);
  ee_kernel<<<1, TB, 0, stream>>>(eEmb, fceW, attn_e, eew);

  // fused softmax + aggregation + residual + LN
  agg_ln_kernel<<<NROWS / 4, TB, 0, stream>>>(rowptr, counts, eidx, hproj,
                                              el, er, eew, gamma, beta,
                                              (float*)d_out);
}

// Round 5
// 304.789 us; speedup vs baseline: 3.4581x; 1.1332x over previous
//
#include <hip/hip_runtime.h>
#include <hip/hip_bf16.h>

#define NPAPER 100000
#define NAUTH  50000
#define NROWS  150000
#define EC 200000
#define EW 100000
#define EB 100000
#define ETOT 400000
#define DIM 256
#define NH 8
#define SLOPE 0.2f
#define LN_EPS 1e-5f

typedef unsigned short u16;
typedef __attribute__((ext_vector_type(8))) short s16x8;
typedef __attribute__((ext_vector_type(4))) float f32x4;

__device__ __forceinline__ float lrelu(float x){ return x >= 0.f ? x : SLOPE * x; }
__device__ __forceinline__ u16 f2b(float f){
  __hip_bfloat16 b = __float2bfloat16(f);
  return *reinterpret_cast<u16*>(&b);
}
__device__ __forceinline__ float b2f(u16 u){
  union { unsigned int i; float f; } v; v.i = ((unsigned int)u) << 16; return v.f;
}

__global__ void fill_i32(int* __restrict__ p, int v, int n){
  int i = blockIdx.x * blockDim.x + threadIdx.x;
  int stride = gridDim.x * blockDim.x;
  for (; i < n; i += stride) p[i] = v;
}

// ---- W f32 -> bf16 ----
__global__ void convert_w(const float4* __restrict__ W4, ushort4* __restrict__ Wb4){
  int i = blockIdx.x * blockDim.x + threadIdx.x;   // 16384 threads
  float4 v = W4[i];
  ushort4 o; o.x = f2b(v.x); o.y = f2b(v.y); o.z = f2b(v.z); o.w = f2b(v.w);
  Wb4[i] = o;
}

// ---- projection via MFMA: hprojb[r,:] = bf16( X[r,:] @ W^T ) ----
#define XPAD 264
__global__ __launch_bounds__(256) void proj_mfma(
    const float* __restrict__ X, const u16* __restrict__ Wb,
    u16* __restrict__ out, int nrows)
{
  const int tid = threadIdx.x;
  const int r0 = blockIdx.x * 64;
  __shared__ u16 xs[64][XPAD];

  for (int i = tid; i < 64 * 64; i += 256){
    int row = i >> 6, c4 = (i & 63) << 2;
    int gr = r0 + row;
    float4 v;
    if (gr < nrows) v = *reinterpret_cast<const float4*>(X + (size_t)gr * DIM + c4);
    else { v.x = v.y = v.z = v.w = 0.f; }
    ushort4 o; o.x = f2b(v.x); o.y = f2b(v.y); o.z = f2b(v.z); o.w = f2b(v.w);
    *reinterpret_cast<ushort4*>(&xs[row][c4]) = o;
  }
  __syncthreads();

  const int l = tid & 63, wid = tid >> 6;
  const int lrow = l & 15;
  const int lk8 = (l >> 4) * 8;
  const int n0 = wid * 64;

  f32x4 acc[4][4];
  #pragma unroll
  for (int mi = 0; mi < 4; mi++)
    #pragma unroll
    for (int ni = 0; ni < 4; ni++) acc[mi][ni] = (f32x4){0.f, 0.f, 0.f, 0.f};

  #pragma unroll
  for (int kk = 0; kk < DIM; kk += 32){
    s16x8 aF[4], bF[4];
    #pragma unroll
    for (int mi = 0; mi < 4; mi++)
      aF[mi] = *reinterpret_cast<const s16x8*>(&xs[mi * 16 + lrow][kk + lk8]);
    #pragma unroll
    for (int ni = 0; ni < 4; ni++){
      int col = n0 + ni * 16 + lrow;
      bF[ni] = *reinterpret_cast<const s16x8*>(Wb + (size_t)col * DIM + kk + lk8);
    }
    #pragma unroll
    for (int mi = 0; mi < 4; mi++)
      #pragma unroll
      for (int ni = 0; ni < 4; ni++)
        acc[mi][ni] = __builtin_amdgcn_mfma_f32_16x16x32_bf16(aF[mi], bF[ni], acc[mi][ni], 0, 0, 0);
  }

  // C frag: col=lane&15, row=(lane>>4)*4+reg
  #pragma unroll
  for (int mi = 0; mi < 4; mi++){
    int rbase = r0 + mi * 16 + (l >> 4) * 4;
    #pragma unroll
    for (int ni = 0; ni < 4; ni++){
      int col = n0 + ni * 16 + lrow;
      #pragma unroll
      for (int reg = 0; reg < 4; reg++){
        int r = rbase + reg;
        if (r < nrows) out[(size_t)r * DIM + col] = f2b(acc[mi][ni][reg]);
      }
    }
  }
}

// ---- el/er head reductions over bf16 hproj ----
__global__ __launch_bounds__(256) void elr_kernel(const u16* __restrict__ hprojb,
    const float* __restrict__ attn_l, const float* __restrict__ attn_r,
    float* __restrict__ el, float* __restrict__ er)
{
  const int wid = threadIdx.x >> 6, l = threadIdx.x & 63;
  const int row = blockIdx.x * 4 + wid;
  if (row >= NROWS) return;
  ushort4 u = *reinterpret_cast<const ushort4*>(hprojb + (size_t)row * DIM + l * 4);
  float v0 = b2f(u.x), v1 = b2f(u.y), v2 = b2f(u.z), v3 = b2f(u.w);
  float4 al = *reinterpret_cast<const float4*>(attn_l + l * 4);
  float4 ar = *reinterpret_cast<const float4*>(attn_r + l * 4);
  float sl = v0*al.x + v1*al.y + v2*al.z + v3*al.w;
  float sr = v0*ar.x + v1*ar.y + v2*ar.z + v3*ar.w;
  #pragma unroll
  for (int m = 1; m < 8; m <<= 1){
    sl += __shfl_xor(sl, m, 64);
    sr += __shfl_xor(sr, m, 64);
  }
  if ((l & 7) == 0){
    int h = l >> 3;
    el[(size_t)row*NH+h] = sl;
    er[(size_t)row*NH+h] = sr;
  }
}

// ---- relation/edge-type term ----
__global__ void ee_kernel(const float* __restrict__ eEmb, const float* __restrict__ fceW,
                          const float* __restrict__ attn_e, float* __restrict__ ee)
{
  const int o = threadIdx.x;
  const float ae = attn_e[o];
  const float* wrow = fceW + (size_t)o * DIM;
  for (int rel = 0; rel < 3; rel++){
    float acc = 0.f;
    for (int k = 0; k < DIM; k++) acc += eEmb[rel * DIM + k] * wrow[k];
    float v = acc * ae;
    #pragma unroll
    for (int m = 16; m > 0; m >>= 1) v += __shfl_xor(v, m, 32);
    if ((o & 31) == 0) ee[rel * NH + (o >> 5)] = v;
  }
}

// ---- CSR build: one fused count pass over all 3 edge lists ----
__global__ void count_all(const int* __restrict__ c_dst, const int* __restrict__ w_dst,
                          const int* __restrict__ b_dst, int* __restrict__ counts){
  int i = blockIdx.x * blockDim.x + threadIdx.x;
  if (i < EC)            atomicAdd(&counts[c_dst[i]], 1);
  else if (i < EC + EW)  atomicAdd(&counts[w_dst[i - EC]], 1);
  else if (i < ETOT)     atomicAdd(&counts[NPAPER + b_dst[i - EC - EW]], 1);
}

__global__ void scan1(const int* __restrict__ in, int* __restrict__ out,
                      int* __restrict__ bsum, int n){
  __shared__ int sh[256];
  int b = blockIdx.x, t = threadIdx.x;
  int base = b * 1024 + t * 4;
  int v0 = (base+0 < n) ? in[base+0] : 0;
  int v1 = (base+1 < n) ? in[base+1] : 0;
  int v2 = (base+2 < n) ? in[base+2] : 0;
  int v3 = (base+3 < n) ? in[base+3] : 0;
  sh[t] = v0+v1+v2+v3;
  __syncthreads();
  for (int off = 1; off < 256; off <<= 1){
    int x = (t >= off) ? sh[t-off] : 0;
    __syncthreads();
    sh[t] += x;
    __syncthreads();
  }
  if (t == 255) bsum[b] = sh[255];
  int run = (t > 0) ? sh[t-1] : 0;
  if (base+0 < n){ out[base+0] = run; run += v0; }
  if (base+1 < n){ out[base+1] = run; run += v1; }
  if (base+2 < n){ out[base+2] = run; run += v2; }
  if (base+3 < n){ out[base+3] = run; }
}

__global__ void scan2(int* __restrict__ bsum, int nb){
  __shared__ int sh[256];
  int t = threadIdx.x;
  sh[t] = (t < nb) ? bsum[t] : 0;
  __syncthreads();
  for (int off = 1; off < 256; off <<= 1){
    int x = (t >= off) ? sh[t-off] : 0;
    __syncthreads();
    sh[t] += x;
    __syncthreads();
  }
  int excl = (t > 0) ? sh[t-1] : 0;
  if (t < nb) bsum[t] = excl;
}

__global__ void scan3(int* __restrict__ rowptr, const int* __restrict__ bsum, int n){
  int i = blockIdx.x * blockDim.x + threadIdx.x;
  if (i < n) rowptr[i] += bsum[i >> 10];
}

__global__ void scatter_all(const int* __restrict__ c_src, const int* __restrict__ c_dst,
                            const int* __restrict__ w_src, const int* __restrict__ w_dst,
                            const int* __restrict__ b_src, const int* __restrict__ b_dst,
                            const int* __restrict__ rowptr, int* __restrict__ cursor,
                            int* __restrict__ eidx){
  int i = blockIdx.x * blockDim.x + threadIdx.x;
  int gd, pk;
  if (i < EC)           { gd = c_dst[i];                pk = c_src[i]; }
  else if (i < EC + EW) { gd = w_dst[i - EC];           pk = (w_src[i - EC] + NPAPER) | (1 << 20); }
  else if (i < ETOT)    { gd = NPAPER + b_dst[i - EC - EW]; pk = b_src[i - EC - EW] | (2 << 20); }
  else return;
  int pos = rowptr[gd] + atomicAdd(&cursor[gd], 1);
  eidx[pos] = pk;
}

// ---- fused: softmax-z + weighted bf16 gather + residual + LN; one wave/row ----
__global__ __launch_bounds__(256) void agg_ln_kernel(
    const int* __restrict__ rowptr, const int* __restrict__ counts,
    const int* __restrict__ eidx, const u16* __restrict__ hprojb,
    const float* __restrict__ el, const float* __restrict__ er,
    const float* __restrict__ eew, const float* __restrict__ gamma,
    const float* __restrict__ beta, float* __restrict__ out)
{
  const int wid = threadIdx.x >> 6, l = threadIdx.x & 63;
  const int r = blockIdx.x * 4 + wid;
  if (r >= NROWS) return;
  const int h = l >> 3;                           // cols 4l..4l+3 share head
  const float er_h = er[(size_t)r * NH + h];
  const int rp = rowptr[r], deg = counts[r];

  float ax = 0.f, ay = 0.f, az = 0.f, aw = 0.f, zl = 0.f;
  for (int e = 0; e < deg; e++){
    int p = eidx[rp + e];
    int gs = p & 0xFFFFF, rel = p >> 20;
    float sc = el[(size_t)gs * NH + h] + er_h + eew[rel * NH + h];
    float w = __expf(lrelu(sc));
    zl += w;
    ushort4 u = *reinterpret_cast<const ushort4*>(hprojb + (size_t)gs * DIM + l * 4);
    ax += w * b2f(u.x); ay += w * b2f(u.y); az += w * b2f(u.z); aw += w * b2f(u.w);
  }
  float iz = (deg > 0) ? 1.f / zl : 0.f;
  ushort4 hr = *reinterpret_cast<const ushort4*>(hprojb + (size_t)r * DIM + l * 4);
  float x0 = lrelu(ax * iz + b2f(hr.x));
  float x1 = lrelu(ay * iz + b2f(hr.y));
  float x2 = lrelu(az * iz + b2f(hr.z));
  float x3 = lrelu(aw * iz + b2f(hr.w));
  float s = x0 + x1 + x2 + x3;
  float q = x0*x0 + x1*x1 + x2*x2 + x3*x3;
  #pragma unroll
  for (int m = 32; m > 0; m >>= 1){
    s += __shfl_xor(s, m, 64);
    q += __shfl_xor(q, m, 64);
  }
  float mu  = s * (1.f / DIM);
  float var = q * (1.f / DIM) - mu * mu;
  float inv = rsqrtf(var + LN_EPS);
  float4 g  = *reinterpret_cast<const float4*>(gamma + l * 4);
  float4 bt = *reinterpret_cast<const float4*>(beta + l * 4);
  float4 o;
  o.x = (x0 - mu) * inv * g.x + bt.x;
  o.y = (x1 - mu) * inv * g.y + bt.y;
  o.z = (x2 - mu) * inv * g.z + bt.z;
  o.w = (x3 - mu) * inv * g.w + bt.w;
  *reinterpret_cast<float4*>(out + (size_t)r * DIM + l * 4) = o;
}

extern "C" void kernel_launch(void* const* d_in, const int* in_sizes, int n_in,
                              void* d_out, int out_size, void* d_ws, size_t ws_size,
                              hipStream_t stream)
{
  const float* hP     = (const float*)d_in[0];
  const float* hA     = (const float*)d_in[1];
  const float* fcW    = (const float*)d_in[2];
  const float* fceW   = (const float*)d_in[3];
  const float* eEmb   = (const float*)d_in[4];
  const float* attn_l = (const float*)d_in[5];
  const float* attn_r = (const float*)d_in[6];
  const float* attn_e = (const float*)d_in[7];
  const float* gamma  = (const float*)d_in[8];
  const float* beta   = (const float*)d_in[9];
  const int* c_src  = (const int*)d_in[10];
  const int* c_dst  = (const int*)d_in[11];
  const int* w_src  = (const int*)d_in[12];
  const int* w_dst  = (const int*)d_in[13];
  const int* b_src  = (const int*)d_in[14];
  const int* b_dst  = (const int*)d_in[15];

  u16*   hprojb = (u16*)d_ws;                           // [NROWS,256] bf16
  float* el    = (float*)(hprojb + (size_t)NROWS * DIM);// [NROWS,8]
  float* er    = el    + (size_t)NROWS * NH;            // [NROWS,8]
  float* eew   = er    + (size_t)NROWS * NH;            // 24 (+pad 32)
  int*   counts= (int*)(eew + 32);                      // [NROWS]
  int*   cursor= counts + NROWS;                        // [NROWS]
  int*   rowptr= cursor + NROWS;                        // [NROWS]
  int*   bsum  = rowptr + NROWS;                        // [256]
  int*   eidx  = bsum + 256;                            // [400000]
  u16*   Wb    = (u16*)(eidx + ETOT);                   // bf16 W

  const int TB = 256;

  // CSR build (independent of projection)
  fill_i32<<<256, TB, 0, stream>>>(counts, 0, 2 * NROWS);   // counts + cursor
  count_all<<<(ETOT + TB - 1) / TB, TB, 0, stream>>>(c_dst, w_dst, b_dst, counts);
  const int NB = (NROWS + 1023) / 1024;                     // 147
  scan1<<<NB, TB, 0, stream>>>(counts, rowptr, bsum, NROWS);
  scan2<<<1, TB, 0, stream>>>(bsum, NB);
  scan3<<<(NROWS + TB - 1) / TB, TB, 0, stream>>>(rowptr, bsum, NROWS);
  scatter_all<<<(ETOT + TB - 1) / TB, TB, 0, stream>>>(c_src, c_dst, w_src, w_dst,
                                                       b_src, b_dst, rowptr, cursor, eidx);

  // projection + attention scalars
  convert_w<<<64, TB, 0, stream>>>((const float4*)fcW, (ushort4*)Wb);
  proj_mfma<<<(NPAPER + 63) / 64, TB, 0, stream>>>(hP, Wb, hprojb, NPAPER);
  proj_mfma<<<(NAUTH  + 63) / 64, TB, 0, stream>>>(hA, Wb, hprojb + (size_t)NPAPER * DIM, NAUTH);
  elr_kernel<<<(NROWS + 3) / 4, TB, 0, stream>>>(hprojb, attn_l, attn_r, el, er);
  ee_kernel<<<1, TB, 0, stream>>>(eEmb, fceW, attn_e, eew);

  // fused softmax + aggregation + residual + LN
  agg_ln_kernel<<<NROWS / 4, TB, 0, stream>>>(rowptr, counts, eidx, hprojb,
                                              el, er, eew, gamma, beta,
                                              (float*)d_out);
}

// Round 6
// 269.991 us; speedup vs baseline: 3.9038x; 1.1289x over previous
//
#include <hip/hip_runtime.h>
#include <hip/hip_bf16.h>

#define NPAPER 100000
#define NAUTH  50000
#define NROWS  150000
#define EC 200000
#define EW 100000
#define EB 100000
#define ETOT 400000
#define DIM 256
#define NH 8
#define SLOPE 0.2f
#define LN_EPS 1e-5f

typedef unsigned short u16;
typedef __attribute__((ext_vector_type(8))) short s16x8;
typedef __attribute__((ext_vector_type(4))) float f32x4;

__device__ __forceinline__ float lrelu(float x){ return x >= 0.f ? x : SLOPE * x; }
__device__ __forceinline__ u16 f2b(float f){
  __hip_bfloat16 b = __float2bfloat16(f);
  return *reinterpret_cast<u16*>(&b);
}
__device__ __forceinline__ float b2f(u16 u){
  union { unsigned int i; float f; } v; v.i = ((unsigned int)u) << 16; return v.f;
}

__global__ void fill_i32(int* __restrict__ p, int v, int n){
  int i = blockIdx.x * blockDim.x + threadIdx.x;
  int stride = gridDim.x * blockDim.x;
  for (; i < n; i += stride) p[i] = v;
}

// ---- W f32 -> bf16 ----
__global__ void convert_w(const float4* __restrict__ W4, ushort4* __restrict__ Wb4){
  int i = blockIdx.x * blockDim.x + threadIdx.x;   // 16384 threads
  float4 v = W4[i];
  ushort4 o; o.x = f2b(v.x); o.y = f2b(v.y); o.z = f2b(v.z); o.w = f2b(v.w);
  Wb4[i] = o;
}

// ---- unified projection via MFMA + fused el/er epilogue ----
// hprojb[r,:] = bf16( X[r,:] @ W^T );  el[r,h]=sum(hp*attn_l), er likewise.
#define XPAD 264
__global__ __launch_bounds__(256) void proj_mfma(
    const float* __restrict__ hP, const float* __restrict__ hA,
    const u16* __restrict__ Wb,
    const float* __restrict__ attn_l, const float* __restrict__ attn_r,
    u16* __restrict__ out, float* __restrict__ el, float* __restrict__ er)
{
  const int tid = threadIdx.x;
  const int r0 = blockIdx.x * 64;
  __shared__ u16 xs[64][XPAD];

  for (int i = tid; i < 64 * 64; i += 256){
    int row = i >> 6, c4 = (i & 63) << 2;
    int gr = r0 + row;
    float4 v;
    if (gr < NPAPER)      v = *reinterpret_cast<const float4*>(hP + (size_t)gr * DIM + c4);
    else if (gr < NROWS)  v = *reinterpret_cast<const float4*>(hA + (size_t)(gr - NPAPER) * DIM + c4);
    else { v.x = v.y = v.z = v.w = 0.f; }
    ushort4 o; o.x = f2b(v.x); o.y = f2b(v.y); o.z = f2b(v.z); o.w = f2b(v.w);
    *reinterpret_cast<ushort4*>(&xs[row][c4]) = o;
  }
  __syncthreads();

  const int l = tid & 63, wid = tid >> 6;
  const int lrow = l & 15;
  const int g = l >> 4;
  const int lk8 = g * 8;
  const int n0 = wid * 64;

  f32x4 acc[4][4];
  #pragma unroll
  for (int mi = 0; mi < 4; mi++)
    #pragma unroll
    for (int ni = 0; ni < 4; ni++) acc[mi][ni] = (f32x4){0.f, 0.f, 0.f, 0.f};

  #pragma unroll
  for (int kk = 0; kk < DIM; kk += 32){
    s16x8 aF[4], bF[4];
    #pragma unroll
    for (int mi = 0; mi < 4; mi++)
      aF[mi] = *reinterpret_cast<const s16x8*>(&xs[mi * 16 + lrow][kk + lk8]);
    #pragma unroll
    for (int ni = 0; ni < 4; ni++){
      int col = n0 + ni * 16 + lrow;
      bF[ni] = *reinterpret_cast<const s16x8*>(Wb + (size_t)col * DIM + kk + lk8);
    }
    #pragma unroll
    for (int mi = 0; mi < 4; mi++)
      #pragma unroll
      for (int ni = 0; ni < 4; ni++)
        acc[mi][ni] = __builtin_amdgcn_mfma_f32_16x16x32_bf16(aF[mi], bF[ni], acc[mi][ni], 0, 0, 0);
  }

  // attn vectors at this lane's 4 columns (cols n0+ni*16+lrow)
  float alv[4], arv[4];
  #pragma unroll
  for (int ni = 0; ni < 4; ni++){
    alv[ni] = attn_l[n0 + ni * 16 + lrow];
    arv[ni] = attn_r[n0 + ni * 16 + lrow];
  }

  // C frag: col=lane&15, row=(lane>>4)*4+reg
  #pragma unroll
  for (int mi = 0; mi < 4; mi++){
    int rbase = r0 + mi * 16 + g * 4;
    // bf16 store of projection
    #pragma unroll
    for (int ni = 0; ni < 4; ni++){
      int col = n0 + ni * 16 + lrow;
      #pragma unroll
      for (int reg = 0; reg < 4; reg++){
        int r = rbase + reg;
        if (r < NROWS) out[(size_t)r * DIM + col] = f2b(acc[mi][ni][reg]);
      }
    }
    // fused el/er: heads 2*wid (ni 0,1) and 2*wid+1 (ni 2,3); reduce over lrow
    #pragma unroll
    for (int reg = 0; reg < 4; reg++){
      float e0 = acc[mi][0][reg]*alv[0] + acc[mi][1][reg]*alv[1];
      float e1 = acc[mi][2][reg]*alv[2] + acc[mi][3][reg]*alv[3];
      float f0 = acc[mi][0][reg]*arv[0] + acc[mi][1][reg]*arv[1];
      float f1 = acc[mi][2][reg]*arv[2] + acc[mi][3][reg]*arv[3];
      #pragma unroll
      for (int m = 1; m < 16; m <<= 1){
        e0 += __shfl_xor(e0, m, 64);
        e1 += __shfl_xor(e1, m, 64);
        f0 += __shfl_xor(f0, m, 64);
        f1 += __shfl_xor(f1, m, 64);
      }
      int r = rbase + reg;
      if (lrow == 0 && r < NROWS){
        el[(size_t)r * NH + 2*wid]     = e0;
        el[(size_t)r * NH + 2*wid + 1] = e1;
        er[(size_t)r * NH + 2*wid]     = f0;
        er[(size_t)r * NH + 2*wid + 1] = f1;
      }
    }
  }
}

// ---- relation/edge-type term ----
__global__ void ee_kernel(const float* __restrict__ eEmb, const float* __restrict__ fceW,
                          const float* __restrict__ attn_e, float* __restrict__ ee)
{
  const int o = threadIdx.x;
  const float ae = attn_e[o];
  const float* wrow = fceW + (size_t)o * DIM;
  for (int rel = 0; rel < 3; rel++){
    float acc = 0.f;
    for (int k = 0; k < DIM; k++) acc += eEmb[rel * DIM + k] * wrow[k];
    float v = acc * ae;
    #pragma unroll
    for (int m = 16; m > 0; m >>= 1) v += __shfl_xor(v, m, 32);
    if ((o & 31) == 0) ee[rel * NH + (o >> 5)] = v;
  }
}

// ---- CSR build ----
__global__ void count_all(const int* __restrict__ c_dst, const int* __restrict__ w_dst,
                          const int* __restrict__ b_dst, int* __restrict__ counts){
  int i = blockIdx.x * blockDim.x + threadIdx.x;
  if (i < EC)            atomicAdd(&counts[c_dst[i]], 1);
  else if (i < EC + EW)  atomicAdd(&counts[w_dst[i - EC]], 1);
  else if (i < ETOT)     atomicAdd(&counts[NPAPER + b_dst[i - EC - EW]], 1);
}

__global__ void scan1(const int* __restrict__ in, int* __restrict__ out,
                      int* __restrict__ bsum, int n){
  __shared__ int sh[256];
  int b = blockIdx.x, t = threadIdx.x;
  int base = b * 1024 + t * 4;
  int v0 = (base+0 < n) ? in[base+0] : 0;
  int v1 = (base+1 < n) ? in[base+1] : 0;
  int v2 = (base+2 < n) ? in[base+2] : 0;
  int v3 = (base+3 < n) ? in[base+3] : 0;
  sh[t] = v0+v1+v2+v3;
  __syncthreads();
  for (int off = 1; off < 256; off <<= 1){
    int x = (t >= off) ? sh[t-off] : 0;
    __syncthreads();
    sh[t] += x;
    __syncthreads();
  }
  if (t == 255) bsum[b] = sh[255];
  int run = (t > 0) ? sh[t-1] : 0;
  if (base+0 < n){ out[base+0] = run; run += v0; }
  if (base+1 < n){ out[base+1] = run; run += v1; }
  if (base+2 < n){ out[base+2] = run; run += v2; }
  if (base+3 < n){ out[base+3] = run; }
}

__global__ void scan2(int* __restrict__ bsum, int nb){
  __shared__ int sh[256];
  int t = threadIdx.x;
  sh[t] = (t < nb) ? bsum[t] : 0;
  __syncthreads();
  for (int off = 1; off < 256; off <<= 1){
    int x = (t >= off) ? sh[t-off] : 0;
    __syncthreads();
    sh[t] += x;
    __syncthreads();
  }
  int excl = (t > 0) ? sh[t-1] : 0;
  if (t < nb) bsum[t] = excl;
}

__global__ void scan3(int* __restrict__ rowptr, const int* __restrict__ bsum, int n){
  int i = blockIdx.x * blockDim.x + threadIdx.x;
  if (i < n) rowptr[i] += bsum[i >> 10];
}

__global__ void scatter_all(const int* __restrict__ c_src, const int* __restrict__ c_dst,
                            const int* __restrict__ w_src, const int* __restrict__ w_dst,
                            const int* __restrict__ b_src, const int* __restrict__ b_dst,
                            const int* __restrict__ rowptr, int* __restrict__ cursor,
                            int* __restrict__ eidx){
  int i = blockIdx.x * blockDim.x + threadIdx.x;
  int gd, pk;
  if (i < EC)           { gd = c_dst[i];                pk = c_src[i]; }
  else if (i < EC + EW) { gd = w_dst[i - EC];           pk = (w_src[i - EC] + NPAPER) | (1 << 20); }
  else if (i < ETOT)    { gd = NPAPER + b_dst[i - EC - EW]; pk = b_src[i - EC - EW] | (2 << 20); }
  else return;
  int pos = rowptr[gd] + atomicAdd(&cursor[gd], 1);
  eidx[pos] = pk;
}

// ---- fused: softmax-z + weighted bf16 gather + residual + LN; one wave/row ----
__global__ __launch_bounds__(256) void agg_ln_kernel(
    const int* __restrict__ rowptr, const int* __restrict__ counts,
    const int* __restrict__ eidx, const u16* __restrict__ hprojb,
    const float* __restrict__ el, const float* __restrict__ er,
    const float* __restrict__ eew, const float* __restrict__ gamma,
    const float* __restrict__ beta, float* __restrict__ out)
{
  const int wid = threadIdx.x >> 6, l = threadIdx.x & 63;
  const int r = blockIdx.x * 4 + wid;
  if (r >= NROWS) return;
  const int h = l >> 3;                           // cols 4l..4l+3 share head
  const float er_h = er[(size_t)r * NH + h];
  const float ee0 = eew[h], ee1 = eew[NH + h], ee2 = eew[2*NH + h];
  const int rp = rowptr[r], deg = counts[r];
  const int end = rp + deg;

  float ax = 0.f, ay = 0.f, az = 0.f, aw = 0.f, zl = 0.f;
  float bx = 0.f, by = 0.f, bz = 0.f, bw = 0.f, z2 = 0.f;
  int e = rp;
  for (; e + 1 < end; e += 2){
    int p0 = eidx[e], p1 = eidx[e + 1];
    int gs0 = p0 & 0xFFFFF, rl0 = p0 >> 20;
    int gs1 = p1 & 0xFFFFF, rl1 = p1 >> 20;
    float sc0 = el[(size_t)gs0 * NH + h] + er_h + (rl0 == 0 ? ee0 : (rl0 == 1 ? ee1 : ee2));
    float sc1 = el[(size_t)gs1 * NH + h] + er_h + (rl1 == 0 ? ee0 : (rl1 == 1 ? ee1 : ee2));
    ushort4 u0 = *reinterpret_cast<const ushort4*>(hprojb + (size_t)gs0 * DIM + l * 4);
    ushort4 u1 = *reinterpret_cast<const ushort4*>(hprojb + (size_t)gs1 * DIM + l * 4);
    float w0 = __expf(lrelu(sc0));
    float w1 = __expf(lrelu(sc1));
    zl += w0; z2 += w1;
    ax += w0 * b2f(u0.x); ay += w0 * b2f(u0.y); az += w0 * b2f(u0.z); aw += w0 * b2f(u0.w);
    bx += w1 * b2f(u1.x); by += w1 * b2f(u1.y); bz += w1 * b2f(u1.z); bw += w1 * b2f(u1.w);
  }
  if (e < end){
    int p0 = eidx[e];
    int gs0 = p0 & 0xFFFFF, rl0 = p0 >> 20;
    float sc0 = el[(size_t)gs0 * NH + h] + er_h + (rl0 == 0 ? ee0 : (rl0 == 1 ? ee1 : ee2));
    ushort4 u0 = *reinterpret_cast<const ushort4*>(hprojb + (size_t)gs0 * DIM + l * 4);
    float w0 = __expf(lrelu(sc0));
    zl += w0;
    ax += w0 * b2f(u0.x); ay += w0 * b2f(u0.y); az += w0 * b2f(u0.z); aw += w0 * b2f(u0.w);
  }
  ax += bx; ay += by; az += bz; aw += bw; zl += z2;

  float iz = (deg > 0) ? 1.f / zl : 0.f;
  ushort4 hr = *reinterpret_cast<const ushort4*>(hprojb + (size_t)r * DIM + l * 4);
  float x0 = lrelu(ax * iz + b2f(hr.x));
  float x1 = lrelu(ay * iz + b2f(hr.y));
  float x2 = lrelu(az * iz + b2f(hr.z));
  float x3 = lrelu(aw * iz + b2f(hr.w));
  float s = x0 + x1 + x2 + x3;
  float q = x0*x0 + x1*x1 + x2*x2 + x3*x3;
  #pragma unroll
  for (int m = 32; m > 0; m >>= 1){
    s += __shfl_xor(s, m, 64);
    q += __shfl_xor(q, m, 64);
  }
  float mu  = s * (1.f / DIM);
  float var = q * (1.f / DIM) - mu * mu;
  float inv = rsqrtf(var + LN_EPS);
  float4 g  = *reinterpret_cast<const float4*>(gamma + l * 4);
  float4 bt = *reinterpret_cast<const float4*>(beta + l * 4);
  float4 o;
  o.x = (x0 - mu) * inv * g.x + bt.x;
  o.y = (x1 - mu) * inv * g.y + bt.y;
  o.z = (x2 - mu) * inv * g.z + bt.z;
  o.w = (x3 - mu) * inv * g.w + bt.w;
  *reinterpret_cast<float4*>(out + (size_t)r * DIM + l * 4) = o;
}

extern "C" void kernel_launch(void* const* d_in, const int* in_sizes, int n_in,
                              void* d_out, int out_size, void* d_ws, size_t ws_size,
                              hipStream_t stream)
{
  const float* hP     = (const float*)d_in[0];
  const float* hA     = (const float*)d_in[1];
  const float* fcW    = (const float*)d_in[2];
  const float* fceW   = (const float*)d_in[3];
  const float* eEmb   = (const float*)d_in[4];
  const float* attn_l = (const float*)d_in[5];
  const float* attn_r = (const float*)d_in[6];
  const float* attn_e = (const float*)d_in[7];
  const float* gamma  = (const float*)d_in[8];
  const float* beta   = (const float*)d_in[9];
  const int* c_src  = (const int*)d_in[10];
  const int* c_dst  = (const int*)d_in[11];
  const int* w_src  = (const int*)d_in[12];
  const int* w_dst  = (const int*)d_in[13];
  const int* b_src  = (const int*)d_in[14];
  const int* b_dst  = (const int*)d_in[15];

  u16*   hprojb = (u16*)d_ws;                           // [NROWS,256] bf16
  float* el    = (float*)(hprojb + (size_t)NROWS * DIM);// [NROWS,8]
  float* er    = el    + (size_t)NROWS * NH;            // [NROWS,8]
  float* eew   = er    + (size_t)NROWS * NH;            // 24 (+pad 32)
  int*   counts= (int*)(eew + 32);                      // [NROWS]
  int*   cursor= counts + NROWS;                        // [NROWS]
  int*   rowptr= cursor + NROWS;                        // [NROWS]
  int*   bsum  = rowptr + NROWS;                        // [256]
  int*   eidx  = bsum + 256;                            // [400000]
  u16*   Wb    = (u16*)(eidx + ETOT);                   // bf16 W

  const int TB = 256;

  // CSR build (independent of projection)
  fill_i32<<<256, TB, 0, stream>>>(counts, 0, 2 * NROWS);   // counts + cursor
  count_all<<<(ETOT + TB - 1) / TB, TB, 0, stream>>>(c_dst, w_dst, b_dst, counts);
  const int NB = (NROWS + 1023) / 1024;                     // 147
  scan1<<<NB, TB, 0, stream>>>(counts, rowptr, bsum, NROWS);
  scan2<<<1, TB, 0, stream>>>(bsum, NB);
  scan3<<<(NROWS + TB - 1) / TB, TB, 0, stream>>>(rowptr, bsum, NROWS);
  scatter_all<<<(ETOT + TB - 1) / TB, TB, 0, stream>>>(c_src, c_dst, w_src, w_dst,
                                                       b_src, b_dst, rowptr, cursor, eidx);

  // projection (+ fused el/er) and relation term
  convert_w<<<64, TB, 0, stream>>>((const float4*)fcW, (ushort4*)Wb);
  proj_mfma<<<(NROWS + 63) / 64, TB, 0, stream>>>(hP, hA, Wb, attn_l, attn_r,
                                                  hprojb, el, er);
  ee_kernel<<<1, TB, 0, stream>>>(eEmb, fceW, attn_e, eew);

  // fused softmax + aggregation + residual + LN
  agg_ln_kernel<<<NROWS / 4, TB, 0, stream>>>(rowptr, counts, eidx, hprojb,
                                              el, er, eew, gamma, beta,
                                              (float*)d_out);
}